// Round 13
// baseline (1921.980 us; speedup 1.0000x reference)
//
#include <hip/hip_runtime.h>
#include <hip/hip_bf16.h>

#pragma clang fp contract(off)

#define DEVI __device__ __forceinline__

constexpr int Bc = 8, Cc = 2048, Vc = 512, Hc = 256;

constexpr int W_N = 23;
constexpr int W_OFF[W_N] = {
  0,        524288,  655360,  655872,  656384,  656896,  787968,  788224,
  984832,   985600,  1051136, 1051392, 1116928, 1117184, 1117440, 1117444,
  1182980,  1183236, 1183748, 1183752, 1249288, 1249544, 1249800 };
constexpr int W_SZ[W_N] = {
  524288, 131072, 512, 512, 512, 131072, 256, 196608, 768,
  65536, 256, 65536, 256, 256, 1, 65536, 256, 512, 2, 65536, 256, 256, 1 };
constexpr int W_TOT = 1249804;
// slots: 0 lit_emb 1 ce_w1 2 ce_b1 3 ce_g 4 ce_beta 5 ce_w2 6 ce_b2
// 7 attn_in_w 8 attn_in_b 9 attn_out_w 10 attn_out_b 11 vs_w1 12 vs_b1
// 13 vs_w2 14 vs_b2 15 ap_w1 16 ap_b1 17 ap_w2 18 ap_b2 19 sp_w1 20 sp_b1
// 21 sp_w2 22 sp_b2

constexpr size_t WT1_O   = 1249808;            // ce_w1^T [256k][512r] (litproj input)
constexpr size_t WT2_O   = WT1_O   + 131072;   // ce_w2^T [512k][256r] (k_combine input)
constexpr size_t WTIN_O  = WT2_O   + 131072;   // attn_in^T [256k][768r]
constexpr size_t WTOUT_O = WTIN_O  + 196608;   // attn_out^T[256k][256r]
constexpr size_t WTV1_O  = WTOUT_O + 65536;    // (unused hole)
constexpr size_t WTAP_O  = WTV1_O  + 65536;    // ap_w1^T
constexpr size_t WTSP_O  = WTAP_O  + 65536;    // sp_w1^T
constexpr size_t WCK_O   = WTSP_O  + 65536;    // (Wk·ce_w2)^T [512k][256o]
constexpr size_t WCV_O   = WCK_O   + 131072;   // (Wv·ce_w2)^T
constexpr size_t BCK_O   = WCV_O   + 131072;   // Wk·ce_b2 (256)
constexpr size_t BCV_O   = BCK_O   + 256;      // Wv·ce_b2 (256)
constexpr size_t LP_O    = BCV_O   + 256;      // lit_emb @ ce_w1^T [1024][512]
constexpr size_t KB_O    = LP_O    + 524288;   // head-major [b*8+h][2048][32]
constexpr size_t VB_O    = KB_O    + 4194304;
constexpr size_t VS8_O   = VB_O    + 4194304;  // (8,256)
constexpr size_t OP_O    = VS8_O   + 2048;     // O partials [64bh][4c][32]
constexpr size_t PM_O    = OP_O    + 8192;     // chunk maxima [64][4]
constexpr size_t PL_O    = PM_O    + 256;      // chunk L [64][4]
constexpr size_t FTOT    = PL_O    + 256;      // ~45 MB + int area

// fused transpose specs (into k_convert)
constexpr int    TR_L2C[W_N]  = {0,8,0,0,0,9,0,8,0,8,0,0,0,0,0,8,0,0,0,8,0,0,0};
constexpr size_t TR_DST[W_N]  = {0,WT1_O,0,0,0,WT2_O,0,WTIN_O,0,WTOUT_O,0,0,0,0,0,WTAP_O,0,0,0,WTSP_O,0,0,0};
constexpr int    TR_ROWS[W_N] = {0,512,0,0,0,256,0,768,0,256,0,0,0,0,0,256,0,0,0,256,0,0,0};

struct SrcPtrs { const void* p[W_N]; };

DEVI float gelu_ref(float x) {
  return (x * (erff(x / 1.41421356237309504880f) + 1.0f)) * 0.5f;
}

__global__ __launch_bounds__(256) void k_detect(const unsigned short* __restrict__ lit,
                                                int* __restrict__ dflag) {
  __shared__ int red[256];
  int t = threadIdx.x, c = 0;
  for (int i = t; i < 4096; i += 256) {
    unsigned e = (lit[i] >> 7) & 0xFF;
    if (e >= 0x8F) c++;
  }
  red[t] = c;
  __syncthreads();
  for (int s = 128; s > 0; s >>= 1) {
    if (t < s) red[t] += red[t + s];
    __syncthreads();
  }
  if (t == 0) dflag[0] = (red[0] > 64) ? 1 : 0;
}

// convert + fused transpose copies
__global__ __launch_bounds__(256) void k_convert(SrcPtrs sp, float* __restrict__ wf,
                                                 const int* __restrict__ dflag) {
  int idx = blockIdx.x * 256 + threadIdx.x;
  if (idx >= W_TOT) return;
  const int isf32 = dflag[0];
  int i = 0;
  while (i + 1 < W_N && idx >= W_OFF[i + 1]) i++;
  int j = idx - W_OFF[i];
  float v = 0.f;
  if (j < W_SZ[i]) {
    if (isf32) v = ((const float*)sp.p[i])[j];
    else {
      unsigned int u = (unsigned int)((const unsigned short*)sp.p[i])[j] << 16;
      v = __uint_as_float(u);
    }
    int l2c = TR_L2C[i];
    if (l2c) {
      int r = j >> l2c, c = j & ((1 << l2c) - 1);
      wf[TR_DST[i] + (size_t)c * TR_ROWS[i] + r] = v;
    }
  }
  wf[idx] = v;
}

// Wck[k][o];  bck[o] = sum_m ce_b2[m]*Wk[o][m]
__global__ __launch_bounds__(256) void k_combine(float* __restrict__ wf) {
  const int blk = blockIdx.x, t = threadIdx.x;
  const float* wtin = wf + WTIN_O;
  if (blk < 512) {
    __shared__ float w2row[256];
    w2row[t] = wf[WT2_O + (size_t)blk * 256 + t];
    __syncthreads();
    float aK = 0.f, aV = 0.f;
    for (int m = 0; m < 256; ++m) {
      float w2 = w2row[m];
      aK = fmaf(w2, wtin[(size_t)m * 768 + 256 + t], aK);
      aV = fmaf(w2, wtin[(size_t)m * 768 + 512 + t], aV);
    }
    wf[WCK_O + (size_t)blk * 256 + t] = aK;
    wf[WCV_O + (size_t)blk * 256 + t] = aV;
  } else {
    float aK = 0.f, aV = 0.f;
    for (int m = 0; m < 256; ++m) {
      float b2 = wf[W_OFF[6] + m];
      aK = fmaf(b2, wtin[(size_t)m * 768 + 256 + t], aK);
      aV = fmaf(b2, wtin[(size_t)m * 768 + 512 + t], aV);
    }
    wf[BCK_O + t] = aK;
    wf[BCV_O + t] = aV;
  }
}

// LP = lit_emb @ ce_w1^T  (1024 x 512)
__global__ __launch_bounds__(256) void k_litproj(float* __restrict__ wf) {
  __shared__ __align__(16) float xs[16][256];
  const int t = threadIdx.x;
  const int l0 = blockIdx.x * 16;
  const float* lit = wf + W_OFF[0];
  for (int r = 0; r < 16; ++r)
    xs[r][t] = lit[(size_t)(l0 + r) * 256 + t];
  __syncthreads();
  const float* w1t = wf + WT1_O;
  float a0[16], a1[16];
  #pragma unroll
  for (int r = 0; r < 16; ++r) { a0[r] = 0.f; a1[r] = 0.f; }
  for (int k = 0; k < 256; k += 4) {
    float wa0 = w1t[(size_t)(k+0)*512 + t], wa1 = w1t[(size_t)(k+1)*512 + t];
    float wa2 = w1t[(size_t)(k+2)*512 + t], wa3 = w1t[(size_t)(k+3)*512 + t];
    float wb0 = w1t[(size_t)(k+0)*512 + 256 + t], wb1 = w1t[(size_t)(k+1)*512 + 256 + t];
    float wb2 = w1t[(size_t)(k+2)*512 + 256 + t], wb3 = w1t[(size_t)(k+3)*512 + 256 + t];
    #pragma unroll
    for (int r = 0; r < 16; ++r) {
      float4 x4 = *(const float4*)&xs[r][k];
      a0[r] = fmaf(x4.x, wa0, a0[r]);
      a0[r] = fmaf(x4.y, wa1, a0[r]);
      a0[r] = fmaf(x4.z, wa2, a0[r]);
      a0[r] = fmaf(x4.w, wa3, a0[r]);
      a1[r] = fmaf(x4.x, wb0, a1[r]);
      a1[r] = fmaf(x4.y, wb1, a1[r]);
      a1[r] = fmaf(x4.z, wb2, a1[r]);
      a1[r] = fmaf(x4.w, wb3, a1[r]);
    }
  }
  float* LP = wf + LP_O;
  for (int r = 0; r < 16; ++r) {
    LP[(size_t)(l0 + r) * 512 + t] = a0[r];
    LP[(size_t)(l0 + r) * 512 + 256 + t] = a1[r];
  }
}

// ctrl layout: [0]=done, [1]=gbar(monotonic), [2]=grel(monotonic),
// [4..11]=confA per it, [12..19]=unaA per it, [20..27]=batcnt (monotonic)
__global__ __launch_bounds__(256) void k_init(float* __restrict__ vs8,
    int* __restrict__ assign, int* __restrict__ ctrl) {
  int idx = blockIdx.x * 256 + threadIdx.x;   // grid covers 4096
  assign[idx] = 2;
  if (idx < 2048) vs8[idx] = 0.f;
  if (idx < 32) ctrl[idx] = 0;
}

// ---------------- clause embedding: LP gather + LN + gelu + GEMM2 ----------------
__global__ __launch_bounds__(256) void k_base(const int* __restrict__ formula,
    const float* __restrict__ wf, float* __restrict__ Kb, float* __restrict__ Vb) {
  __shared__ __align__(16) float h1[16][516];
  __shared__ float red2[16][16];
  __shared__ float mv[16], vr[16];
  const int t = threadIdx.x;
  const int n0 = blockIdx.x * 16;
  const float* LP = wf + LP_O;
  const float* b1 = wf + W_OFF[2];
  for (int r = 0; r < 16; ++r) {
    int n = n0 + r;
    const float* p0 = LP + (size_t)formula[n*3+0] * 512;
    const float* p1 = LP + (size_t)formula[n*3+1] * 512;
    const float* p2 = LP + (size_t)formula[n*3+2] * 512;
    for (int c = t; c < 512; c += 256)
      h1[r][c] = (p0[c] + p1[c] + p2[c]) / 3.0f + b1[c];
  }
  __syncthreads();
  {
    const int r = t >> 4, l16 = t & 15;
    float s = 0.f;
    for (int j = 0; j < 32; ++j) s += h1[r][l16 + j * 16];
    red2[r][l16] = s;
  }
  __syncthreads();
  if (t < 16) {
    float s = 0.f;
    for (int i = 0; i < 16; ++i) s += red2[t][i];
    mv[t] = s / 512.0f;
  }
  __syncthreads();
  {
    const int r = t >> 4, l16 = t & 15;
    float m = mv[r], v = 0.f;
    for (int j = 0; j < 32; ++j) { float d = h1[r][l16 + j * 16] - m; v += d * d; }
    red2[r][l16] = v;
  }
  __syncthreads();
  if (t < 16) {
    float s = 0.f;
    for (int i = 0; i < 16; ++i) s += red2[t][i];
    vr[t] = s / 512.0f;
  }
  __syncthreads();
  {
    const float* g  = wf + W_OFF[3];
    const float* be = wf + W_OFF[4];
    for (int r = 0; r < 16; ++r) {
      float sd = sqrtf(vr[r] + 1e-5f);
      for (int c = t; c < 512; c += 256) {
        float val = (h1[r][c] - mv[r]) / sd * g[c] + be[c];
        h1[r][c] = gelu_ref(val);
      }
    }
  }
  __syncthreads();
  {
    const float* wck = wf + WCK_O;
    const float* wcv = wf + WCV_O;
    float aK[16], aV[16];
    #pragma unroll
    for (int r = 0; r < 16; ++r) { aK[r] = 0.f; aV[r] = 0.f; }
    for (int k = 0; k < 512; k += 4) {
      float ck0 = wck[(size_t)(k+0)*256 + t], ck1 = wck[(size_t)(k+1)*256 + t];
      float ck2 = wck[(size_t)(k+2)*256 + t], ck3 = wck[(size_t)(k+3)*256 + t];
      float cv0 = wcv[(size_t)(k+0)*256 + t], cv1 = wcv[(size_t)(k+1)*256 + t];
      float cv2 = wcv[(size_t)(k+2)*256 + t], cv3 = wcv[(size_t)(k+3)*256 + t];
      #pragma unroll
      for (int r = 0; r < 16; ++r) {
        float4 x4 = *(const float4*)&h1[r][k];
        aK[r] = fmaf(x4.x, ck0, aK[r]);
        aK[r] = fmaf(x4.y, ck1, aK[r]);
        aK[r] = fmaf(x4.z, ck2, aK[r]);
        aK[r] = fmaf(x4.w, ck3, aK[r]);
        aV[r] = fmaf(x4.x, cv0, aV[r]);
        aV[r] = fmaf(x4.y, cv1, aV[r]);
        aV[r] = fmaf(x4.z, cv2, aV[r]);
        aV[r] = fmaf(x4.w, cv3, aV[r]);
      }
    }
    float bck = wf[BCK_O + t], bcv = wf[BCV_O + t];
    const int h = t >> 5, d = t & 31;
    for (int r = 0; r < 16; ++r) {
      int n = n0 + r;
      int b = n >> 11, j = n & 2047;
      size_t off = ((size_t)(b * 8 + h) * 2048 + j) * 32 + d;
      Kb[off] = aK[r] + bck;
      Vb[off] = aV[r] + bcv;
    }
  }
}

// ---------------- persistent 8-iteration loop kernel ----------------
// 256 blocks = 64 bh * 4 chunks, 1 block/CU. K/V chunk pinned in LDS
// (K transposed kT[32][516], V padded vsd[512][33] — both conflict-free).
// Iterations separated by monotonic-counter barriers (R11/12-validated
// fence discipline). All arithmetic orders identical to R12.
__global__ __launch_bounds__(256) void k_loop(const int* __restrict__ formula,
    const float* __restrict__ Kb, const float* __restrict__ Vb,
    const float* __restrict__ wf, float* __restrict__ vs8,
    float* __restrict__ op, float* __restrict__ pm, float* __restrict__ pl,
    int* __restrict__ assign, int* __restrict__ selb, int* __restrict__ ctrl) {
  __shared__ float kT[32 * 516];
  __shared__ float vsd[512 * 33];
  __shared__ float xv[256], qs[32], qpart[8][32];
  __shared__ float sS[512], sF[512], sRed[256];
  __shared__ float sO[8][32];
  __shared__ float sM, sQB;
  __shared__ float xo[256], hh[256];
  __shared__ int ssel, sna, sconf, suna, slastS, sglast, sdone, sac, sua;
  const int blk = blockIdx.x;
  const int bh = blk >> 2, c = blk & 3;
  const int b = bh >> 3, h = bh & 7;
  const int t = threadIdx.x;
  const float FAC1 = 1.0f - 0.9f;

  // one-time K/V chunk load into LDS
  {
    const float* kbh = Kb + ((size_t)bh * 2048 + c * 512) * 32;
    const float* vbh = Vb + ((size_t)bh * 2048 + c * 512) * 32;
    for (int base = 0; base < 64; ++base) {
      int idx = base * 256 + t;
      int j = idx >> 5, d = idx & 31;
      kT[d * 516 + j] = kbh[idx];
      vsd[j * 33 + d] = vbh[idx];
    }
  }
  __syncthreads();

  for (int it = 0; it < 8; ++it) {
    xv[t] = vs8[b * 256 + t];
    __syncthreads();
    // q projection: 8 partial chains of 32 k each, tree-combined
    {
      const float* wt = wf + WTIN_O;
      const int cc = h * 32 + (t & 31), seg = t >> 5;
      float part = 0.f;
      for (int k = seg * 32; k < seg * 32 + 32; ++k)
        part = fmaf(xv[k], wt[(size_t)k * 768 + cc], part);
      qpart[seg][t & 31] = part;
    }
    __syncthreads();
    if (t < 32) {
      float acc = qpart[0][t];
      #pragma unroll
      for (int s = 1; s < 8; ++s) acc += qpart[s][t];
      qs[t] = acc + wf[W_OFF[8] + h * 32 + t];
    }
    __syncthreads();
    if (t == 0) {
      const float* bk = wf + W_OFF[8] + 256;
      float s = 0.f;
      for (int d = 0; d < 32; ++d) s = fmaf(qs[d], bk[h * 32 + d], s);
      sQB = s;
    }
    __syncthreads();
    float qreg[32];
    #pragma unroll
    for (int d = 0; d < 32; ++d) qreg[d] = qs[d];
    const float qb = sQB;

    // phase A: s, fac, chunk max (K from LDS, d-ascending chain)
    float mloc = -3.402823466e38f;
    #pragma unroll
    for (int ii = 0; ii < 2; ++ii) {
      int jl = ii * 256 + t;
      int n = b * 2048 + c * 512 + jl;
      bool sat = false;
      #pragma unroll
      for (int l = 0; l < 3; ++l) {
        int f = formula[n * 3 + l];
        int a = assign[b * 512 + (f >> 1)];
        sat = sat || (a == (f & 1));
      }
      float fac = sat ? FAC1 : 1.0f;
      float p = 0.f;
      #pragma unroll
      for (int d = 0; d < 32; ++d)
        p = fmaf(qreg[d], kT[d * 516 + jl], p);
      float s = fmaf(fac, p, qb);
      sS[jl] = s; sF[jl] = fac;
      mloc = fmaxf(mloc, s);
    }
    sRed[t] = mloc;
    __syncthreads();
    for (int st = 128; st > 0; st >>= 1) {
      if (t < st) sRed[t] = fmaxf(sRed[t], sRed[t + st]);
      __syncthreads();
    }
    if (t == 0) sM = sRed[0];
    __syncthreads();
    const float Mc = sM;

    // phase B1: u, Lc, w = u*fac
    {
      float u0 = expf(sS[t * 2] - Mc);
      float u1 = expf(sS[t * 2 + 1] - Mc);
      float ll = u0 + u1;
      sS[t * 2] = u0 * sF[t * 2];
      sS[t * 2 + 1] = u1 * sF[t * 2 + 1];
      __syncthreads();
      sRed[t] = ll;
      __syncthreads();
      for (int st = 128; st > 0; st >>= 1) {
        if (t < st) sRed[t] = sRed[t] + sRed[t + st];
        __syncthreads();
      }
    }
    // phase B2: PV partials (V from LDS)
    {
      const int jg = t >> 5, d = t & 31;
      float acc = 0.f;
      for (int jj = 0; jj < 64; ++jj)
        acc = fmaf(sS[jg * 64 + jj], vsd[(jg * 64 + jj) * 33 + d], acc);
      sO[jg][d] = acc;
    }
    __syncthreads();
    if (t < 32) {
      float o = sO[0][t];
      #pragma unroll
      for (int g = 1; g < 8; ++g) o += sO[g][t];
      op[(size_t)(bh * 4 + c) * 32 + t] = o;
      if (t == 0) { pm[bh * 4 + c] = Mc; pl[bh * 4 + c] = sRed[0]; }
    }
    __syncthreads();
    // per-batch arrival (release); monotonic counter
    if (t == 0) {
      __threadfence();
      int old = atomicAdd(&ctrl[20 + b], 1);
      slastS = (old == it * 32 + 31) ? 1 : 0;
    }
    __syncthreads();
    if (slastS) {
      // ---- batch-last block: update phase for batch b ----
      __threadfence();   // acquire
      if (t == 0) { ssel = 512; sconf = 0; suna = 0; }
      {
        const int h2 = t >> 5, d = t & 31, bh2 = b * 8 + h2;
        float m0 = pm[bh2*4+0], m1 = pm[bh2*4+1], m2 = pm[bh2*4+2], m3 = pm[bh2*4+3];
        float M = fmaxf(fmaxf(m0, m1), fmaxf(m2, m3));
        float e0 = expf(m0 - M), e1 = expf(m1 - M), e2 = expf(m2 - M), e3 = expf(m3 - M);
        float den = e0 * pl[bh2*4+0];
        den = fmaf(e1, pl[bh2*4+1], den);
        den = fmaf(e2, pl[bh2*4+2], den);
        den = fmaf(e3, pl[bh2*4+3], den);
        float O = e0 * op[(size_t)(bh2*4+0)*32 + d];
        O = fmaf(e1, op[(size_t)(bh2*4+1)*32 + d], O);
        O = fmaf(e2, op[(size_t)(bh2*4+2)*32 + d], O);
        O = fmaf(e3, op[(size_t)(bh2*4+3)*32 + d], O);
        float bv = wf[W_OFF[8] + 512 + h2 * 32 + d];
        xo[h2 * 32 + d] = O / den + bv;
      }
      __syncthreads();
      {
        const float* wt = wf + WTOUT_O;
        float acc = 0.f;
        for (int k = 0; k < 256; ++k) acc = fmaf(xo[k], wt[(size_t)k * 256 + t], acc);
        float v = acc + wf[W_OFF[10] + t];
        vs8[b * 256 + t] = v;
        xv[t] = v;
      }
      __syncthreads();
      for (int ii = t; ii < 512; ii += 256)
        if (assign[b * 512 + ii] == 2) atomicMin(&ssel, ii);
      __syncthreads();
      const int sel = (ssel == 512) ? 0 : ssel;
      {
        const float* wt = wf + WTAP_O;
        float a = 0.f;
        for (int k = 0; k < 256; ++k) a = fmaf(xv[k], wt[(size_t)k * 256 + t], a);
        hh[t] = gelu_ref(a + wf[W_OFF[16] + t]);
      }
      __syncthreads();
      if (t == 0) {
        const float* w2 = wf + W_OFF[17];
        float l0 = 0.f, l1 = 0.f;
        for (int k = 0; k < 256; ++k) l0 = fmaf(hh[k], w2[k], l0);
        for (int k = 0; k < 256; ++k) l1 = fmaf(hh[k], w2[256 + k], l1);
        l0 += wf[W_OFF[18]];
        l1 += wf[W_OFF[18] + 1];
        int na = (l1 > l0) ? 1 : 0;
        assign[b * 512 + sel] = na;
        atomicExch(&selb[b], sel);
        sna = na;
      }
      __syncthreads();
      const int na = sna;
      int conf = 0, una = 0;
      for (int ii = t; ii < 2048; ii += 256) {
        int n = b * 2048 + ii;
        bool sat = false, alla = true;
        #pragma unroll
        for (int l = 0; l < 3; ++l) {
          int f = formula[n * 3 + l];
          int v = f >> 1;
          int a = (v == sel) ? na : assign[b * 512 + v];
          sat = sat || (a == (f & 1));
          alla = alla && (a != 2);
        }
        if (alla && !sat) conf = 1;
      }
      for (int ii = t; ii < 512; ii += 256) {
        int a = (ii == sel) ? na : assign[b * 512 + ii];
        if (a == 2) una = 1;
      }
      if (conf) atomicOr(&sconf, 1);
      if (una) atomicOr(&suna, 1);
      __syncthreads();
      if (t == 0) {
        if (sconf) atomicOr(&ctrl[4 + it], 1);
        if (suna) atomicOr(&ctrl[12 + it], 1);
        __threadfence();
        int old = atomicAdd(&ctrl[1], 1);
        sglast = (old == it * 8 + 7) ? 1 : 0;
      }
      __syncthreads();
      if (sglast) {
        // ---- global-last block: revert + done latch + release ----
        __threadfence();  // acquire
        if (t == 0) {
          sac = atomicAdd(&ctrl[4 + it], 0);
          sua = atomicAdd(&ctrl[12 + it], 0);
        }
        __syncthreads();
        if (sac && t < 8) {
          int s = atomicAdd(&selb[t], 0);
          assign[t * 512 + s] = 2;
        }
        __syncthreads();
        if (t == 0) {
          if (!sac && !sua) atomicExch(&ctrl[0], 1);
          __threadfence();
          atomicAdd(&ctrl[2], 1);   // grel -> it+1
        }
      }
    }
    // all blocks wait for iteration release
    if (t == 0) {
      while (__hip_atomic_load(&ctrl[2], __ATOMIC_ACQUIRE, __HIP_MEMORY_SCOPE_AGENT) < it + 1)
        __builtin_amdgcn_s_sleep(1);
      sdone = atomicAdd(&ctrl[0], 0);
    }
    __syncthreads();
    __threadfence();   // acquire for vs8/assign reads next iteration
    if (sdone) break;
  }
}

__global__ __launch_bounds__(256) void k_issat(const float* __restrict__ vs8,
    const int* __restrict__ assign, const float* __restrict__ wf,
    void* __restrict__ outv, const int* __restrict__ dflag) {
  const int b = blockIdx.x, t = threadIdx.x;
  const int isf32 = dflag[0];
  __shared__ float x[256], h[256];
  x[t] = vs8[b * 256 + t];   // mean of 512 identical rows == the row
  __syncthreads();
  const float* wt = wf + WTSP_O;
  float a = 0.f;
  for (int k = 0; k < 256; ++k) a = fmaf(x[k], wt[(size_t)k * 256 + t], a);
  h[t] = gelu_ref(a + wf[W_OFF[20] + t]);
  __syncthreads();
  if (t == 0) {
    const float* w2 = wf + W_OFF[21];
    float l = 0.f;
    for (int k = 0; k < 256; ++k) l = fmaf(h[k], w2[k], l);
    l += wf[W_OFF[22]];
    float sig = 1.f / (1.f + expf(-l));
    if (isf32) ((float*)outv)[b] = sig;
    else ((__hip_bfloat16*)outv)[b] = __float2bfloat16(sig);
  }
  for (int i = t; i < 512; i += 256) {
    float av = (float)assign[b * 512 + i];
    if (isf32) ((float*)outv)[8 + b * 512 + i] = av;
    else ((__hip_bfloat16*)outv)[8 + b * 512 + i] = __float2bfloat16(av);
  }
}

extern "C" void kernel_launch(void* const* d_in, const int* in_sizes, int n_in,
                              void* d_out, int out_size, void* d_ws, size_t ws_size,
                              hipStream_t stream) {
  (void)in_sizes; (void)n_in; (void)out_size; (void)ws_size;
  const int* formula = (const int*)d_in[0];
  float* wf = (float*)d_ws;
  SrcPtrs sp;
  for (int i = 0; i < W_N; ++i) sp.p[i] = d_in[i + 1];
  float* Kb   = wf + KB_O;
  float* Vb   = wf + VB_O;
  float* vs8  = wf + VS8_O;
  float* op   = wf + OP_O;
  float* pm   = wf + PM_O;
  float* pl   = wf + PL_O;
  int* iw     = (int*)(wf + FTOT);
  int* assign = iw;
  int* selb   = iw + 4096;
  int* ctrl   = iw + 4104;
  int* dflag  = iw + 4136;

  k_detect<<<1, 256, 0, stream>>>((const unsigned short*)d_in[1], dflag);
  k_convert<<<(W_TOT + 255) / 256, 256, 0, stream>>>(sp, wf, dflag);
  k_combine<<<513, 256, 0, stream>>>(wf);
  k_litproj<<<64, 256, 0, stream>>>(wf);
  k_init<<<16, 256, 0, stream>>>(vs8, assign, ctrl);
  k_base<<<1024, 256, 0, stream>>>(formula, wf, Kb, Vb);
  k_loop<<<256, 256, 0, stream>>>(formula, Kb, Vb, wf, vs8, op, pm, pl,
                                  assign, selb, ctrl);
  k_issat<<<8, 256, 0, stream>>>(vs8, assign, wf, d_out, dflag);
}

// Round 14
// 1909.528 us; speedup vs baseline: 1.0065x; 1.0065x over previous
//
#include <hip/hip_runtime.h>
#include <hip/hip_bf16.h>

#pragma clang fp contract(off)

#define DEVI __device__ __forceinline__

constexpr int Bc = 8, Cc = 2048, Vc = 512, Hc = 256;

constexpr int W_N = 23;
constexpr int W_OFF[W_N] = {
  0,        524288,  655360,  655872,  656384,  656896,  787968,  788224,
  984832,   985600,  1051136, 1051392, 1116928, 1117184, 1117440, 1117444,
  1182980,  1183236, 1183748, 1183752, 1249288, 1249544, 1249800 };
constexpr int W_SZ[W_N] = {
  524288, 131072, 512, 512, 512, 131072, 256, 196608, 768,
  65536, 256, 65536, 256, 256, 1, 65536, 256, 512, 2, 65536, 256, 256, 1 };
constexpr int W_TOT = 1249804;
// slots: 0 lit_emb 1 ce_w1 2 ce_b1 3 ce_g 4 ce_beta 5 ce_w2 6 ce_b2
// 7 attn_in_w 8 attn_in_b 9 attn_out_w 10 attn_out_b 11 vs_w1 12 vs_b1
// 13 vs_w2 14 vs_b2 15 ap_w1 16 ap_b1 17 ap_w2 18 ap_b2 19 sp_w1 20 sp_b1
// 21 sp_w2 22 sp_b2

constexpr size_t WT1_O   = 1249808;            // ce_w1^T [256k][512r] (litproj input)
constexpr size_t WT2_O   = WT1_O   + 131072;   // ce_w2^T [512k][256r] (k_combine input)
constexpr size_t WTIN_O  = WT2_O   + 131072;   // attn_in^T [256k][768r]
constexpr size_t WTOUT_O = WTIN_O  + 196608;   // attn_out^T[256k][256r]
constexpr size_t WTV1_O  = WTOUT_O + 65536;    // (unused hole)
constexpr size_t WTAP_O  = WTV1_O  + 65536;    // ap_w1^T
constexpr size_t WTSP_O  = WTAP_O  + 65536;    // sp_w1^T
constexpr size_t WCK_O   = WTSP_O  + 65536;    // (Wk·ce_w2)^T [512k][256o]
constexpr size_t WCV_O   = WCK_O   + 131072;   // (Wv·ce_w2)^T
constexpr size_t BCK_O   = WCV_O   + 131072;   // Wk·ce_b2 (256)
constexpr size_t BCV_O   = BCK_O   + 256;      // Wv·ce_b2 (256)
constexpr size_t LP_O    = BCV_O   + 256;      // lit_emb @ ce_w1^T [1024][512]
constexpr size_t KB_O    = LP_O    + 524288;   // head-major [b*8+h][2048][32]
constexpr size_t VB_O    = KB_O    + 4194304;
constexpr size_t VS8_O   = VB_O    + 4194304;  // (8,256)
constexpr size_t OP_O    = VS8_O   + 2048;     // O partials [64bh][4c][32]
constexpr size_t PM_O    = OP_O    + 8192;     // chunk maxima [64][4]
constexpr size_t PL_O    = PM_O    + 256;      // chunk L [64][4]
constexpr size_t FTOT    = PL_O    + 256;      // ~45 MB + int area

// ctrl layout (ints), each hot counter on its own 128B line:
// [0]=done  [32]=gbar  [64]=grel  [96+it]=conf  [128+it]=una
// [160+b*32]=batcnt[b]   (total 416, zero 512)
constexpr int C_DONE = 0, C_GBAR = 32, C_GREL = 64, C_CONF = 96, C_UNA = 128, C_BAT = 160;

// fused transpose specs (into k_convert)
constexpr int    TR_L2C[W_N]  = {0,8,0,0,0,9,0,8,0,8,0,0,0,0,0,8,0,0,0,8,0,0,0};
constexpr size_t TR_DST[W_N]  = {0,WT1_O,0,0,0,WT2_O,0,WTIN_O,0,WTOUT_O,0,0,0,0,0,WTAP_O,0,0,0,WTSP_O,0,0,0};
constexpr int    TR_ROWS[W_N] = {0,512,0,0,0,256,0,768,0,256,0,0,0,0,0,256,0,0,0,256,0,0,0};

struct SrcPtrs { const void* p[W_N]; };

DEVI float gelu_ref(float x) {
  return (x * (erff(x / 1.41421356237309504880f) + 1.0f)) * 0.5f;
}

__global__ __launch_bounds__(256) void k_detect(const unsigned short* __restrict__ lit,
                                                int* __restrict__ dflag) {
  __shared__ int red[256];
  int t = threadIdx.x, c = 0;
  for (int i = t; i < 4096; i += 256) {
    unsigned e = (lit[i] >> 7) & 0xFF;
    if (e >= 0x8F) c++;
  }
  red[t] = c;
  __syncthreads();
  for (int s = 128; s > 0; s >>= 1) {
    if (t < s) red[t] += red[t + s];
    __syncthreads();
  }
  if (t == 0) dflag[0] = (red[0] > 64) ? 1 : 0;
}

// convert + fused transpose copies
__global__ __launch_bounds__(256) void k_convert(SrcPtrs sp, float* __restrict__ wf,
                                                 const int* __restrict__ dflag) {
  int idx = blockIdx.x * 256 + threadIdx.x;
  if (idx >= W_TOT) return;
  const int isf32 = dflag[0];
  int i = 0;
  while (i + 1 < W_N && idx >= W_OFF[i + 1]) i++;
  int j = idx - W_OFF[i];
  float v = 0.f;
  if (j < W_SZ[i]) {
    if (isf32) v = ((const float*)sp.p[i])[j];
    else {
      unsigned int u = (unsigned int)((const unsigned short*)sp.p[i])[j] << 16;
      v = __uint_as_float(u);
    }
    int l2c = TR_L2C[i];
    if (l2c) {
      int r = j >> l2c, c = j & ((1 << l2c) - 1);
      wf[TR_DST[i] + (size_t)c * TR_ROWS[i] + r] = v;
    }
  }
  wf[idx] = v;
}

// Wck[k][o];  bck[o] = sum_m ce_b2[m]*Wk[o][m]
__global__ __launch_bounds__(256) void k_combine(float* __restrict__ wf) {
  const int blk = blockIdx.x, t = threadIdx.x;
  const float* wtin = wf + WTIN_O;
  if (blk < 512) {
    __shared__ float w2row[256];
    w2row[t] = wf[WT2_O + (size_t)blk * 256 + t];
    __syncthreads();
    float aK = 0.f, aV = 0.f;
    for (int m = 0; m < 256; ++m) {
      float w2 = w2row[m];
      aK = fmaf(w2, wtin[(size_t)m * 768 + 256 + t], aK);
      aV = fmaf(w2, wtin[(size_t)m * 768 + 512 + t], aV);
    }
    wf[WCK_O + (size_t)blk * 256 + t] = aK;
    wf[WCV_O + (size_t)blk * 256 + t] = aV;
  } else {
    float aK = 0.f, aV = 0.f;
    for (int m = 0; m < 256; ++m) {
      float b2 = wf[W_OFF[6] + m];
      aK = fmaf(b2, wtin[(size_t)m * 768 + 256 + t], aK);
      aV = fmaf(b2, wtin[(size_t)m * 768 + 512 + t], aV);
    }
    wf[BCK_O + t] = aK;
    wf[BCV_O + t] = aV;
  }
}

// LP = lit_emb @ ce_w1^T  (1024 x 512)
__global__ __launch_bounds__(256) void k_litproj(float* __restrict__ wf) {
  __shared__ __align__(16) float xs[16][256];
  const int t = threadIdx.x;
  const int l0 = blockIdx.x * 16;
  const float* lit = wf + W_OFF[0];
  for (int r = 0; r < 16; ++r)
    xs[r][t] = lit[(size_t)(l0 + r) * 256 + t];
  __syncthreads();
  const float* w1t = wf + WT1_O;
  float a0[16], a1[16];
  #pragma unroll
  for (int r = 0; r < 16; ++r) { a0[r] = 0.f; a1[r] = 0.f; }
  for (int k = 0; k < 256; k += 4) {
    float wa0 = w1t[(size_t)(k+0)*512 + t], wa1 = w1t[(size_t)(k+1)*512 + t];
    float wa2 = w1t[(size_t)(k+2)*512 + t], wa3 = w1t[(size_t)(k+3)*512 + t];
    float wb0 = w1t[(size_t)(k+0)*512 + 256 + t], wb1 = w1t[(size_t)(k+1)*512 + 256 + t];
    float wb2 = w1t[(size_t)(k+2)*512 + 256 + t], wb3 = w1t[(size_t)(k+3)*512 + 256 + t];
    #pragma unroll
    for (int r = 0; r < 16; ++r) {
      float4 x4 = *(const float4*)&xs[r][k];
      a0[r] = fmaf(x4.x, wa0, a0[r]);
      a0[r] = fmaf(x4.y, wa1, a0[r]);
      a0[r] = fmaf(x4.z, wa2, a0[r]);
      a0[r] = fmaf(x4.w, wa3, a0[r]);
      a1[r] = fmaf(x4.x, wb0, a1[r]);
      a1[r] = fmaf(x4.y, wb1, a1[r]);
      a1[r] = fmaf(x4.z, wb2, a1[r]);
      a1[r] = fmaf(x4.w, wb3, a1[r]);
    }
  }
  float* LP = wf + LP_O;
  for (int r = 0; r < 16; ++r) {
    LP[(size_t)(l0 + r) * 512 + t] = a0[r];
    LP[(size_t)(l0 + r) * 512 + 256 + t] = a1[r];
  }
}

__global__ __launch_bounds__(256) void k_init(float* __restrict__ vs8,
    int* __restrict__ assign, int* __restrict__ ctrl) {
  int idx = blockIdx.x * 256 + threadIdx.x;   // grid covers 4096
  assign[idx] = 2;
  if (idx < 2048) vs8[idx] = 0.f;
  if (idx < 512) ctrl[idx] = 0;
}

// ---------------- clause embedding: LP gather + LN + gelu + GEMM2 ----------------
__global__ __launch_bounds__(256) void k_base(const int* __restrict__ formula,
    const float* __restrict__ wf, float* __restrict__ Kb, float* __restrict__ Vb) {
  __shared__ __align__(16) float h1[16][516];
  __shared__ float red2[16][16];
  __shared__ float mv[16], vr[16];
  const int t = threadIdx.x;
  const int n0 = blockIdx.x * 16;
  const float* LP = wf + LP_O;
  const float* b1 = wf + W_OFF[2];
  for (int r = 0; r < 16; ++r) {
    int n = n0 + r;
    const float* p0 = LP + (size_t)formula[n*3+0] * 512;
    const float* p1 = LP + (size_t)formula[n*3+1] * 512;
    const float* p2 = LP + (size_t)formula[n*3+2] * 512;
    for (int c = t; c < 512; c += 256)
      h1[r][c] = (p0[c] + p1[c] + p2[c]) / 3.0f + b1[c];
  }
  __syncthreads();
  {
    const int r = t >> 4, l16 = t & 15;
    float s = 0.f;
    for (int j = 0; j < 32; ++j) s += h1[r][l16 + j * 16];
    red2[r][l16] = s;
  }
  __syncthreads();
  if (t < 16) {
    float s = 0.f;
    for (int i = 0; i < 16; ++i) s += red2[t][i];
    mv[t] = s / 512.0f;
  }
  __syncthreads();
  {
    const int r = t >> 4, l16 = t & 15;
    float m = mv[r], v = 0.f;
    for (int j = 0; j < 32; ++j) { float d = h1[r][l16 + j * 16] - m; v += d * d; }
    red2[r][l16] = v;
  }
  __syncthreads();
  if (t < 16) {
    float s = 0.f;
    for (int i = 0; i < 16; ++i) s += red2[t][i];
    vr[t] = s / 512.0f;
  }
  __syncthreads();
  {
    const float* g  = wf + W_OFF[3];
    const float* be = wf + W_OFF[4];
    for (int r = 0; r < 16; ++r) {
      float sd = sqrtf(vr[r] + 1e-5f);
      for (int c = t; c < 512; c += 256) {
        float val = (h1[r][c] - mv[r]) / sd * g[c] + be[c];
        h1[r][c] = gelu_ref(val);
      }
    }
  }
  __syncthreads();
  {
    const float* wck = wf + WCK_O;
    const float* wcv = wf + WCV_O;
    float aK[16], aV[16];
    #pragma unroll
    for (int r = 0; r < 16; ++r) { aK[r] = 0.f; aV[r] = 0.f; }
    for (int k = 0; k < 512; k += 4) {
      float ck0 = wck[(size_t)(k+0)*256 + t], ck1 = wck[(size_t)(k+1)*256 + t];
      float ck2 = wck[(size_t)(k+2)*256 + t], ck3 = wck[(size_t)(k+3)*256 + t];
      float cv0 = wcv[(size_t)(k+0)*256 + t], cv1 = wcv[(size_t)(k+1)*256 + t];
      float cv2 = wcv[(size_t)(k+2)*256 + t], cv3 = wcv[(size_t)(k+3)*256 + t];
      #pragma unroll
      for (int r = 0; r < 16; ++r) {
        float4 x4 = *(const float4*)&h1[r][k];
        aK[r] = fmaf(x4.x, ck0, aK[r]);
        aK[r] = fmaf(x4.y, ck1, aK[r]);
        aK[r] = fmaf(x4.z, ck2, aK[r]);
        aK[r] = fmaf(x4.w, ck3, aK[r]);
        aV[r] = fmaf(x4.x, cv0, aV[r]);
        aV[r] = fmaf(x4.y, cv1, aV[r]);
        aV[r] = fmaf(x4.z, cv2, aV[r]);
        aV[r] = fmaf(x4.w, cv3, aV[r]);
      }
    }
    float bck = wf[BCK_O + t], bcv = wf[BCV_O + t];
    const int h = t >> 5, d = t & 31;
    for (int r = 0; r < 16; ++r) {
      int n = n0 + r;
      int b = n >> 11, j = n & 2047;
      size_t off = ((size_t)(b * 8 + h) * 2048 + j) * 32 + d;
      Kb[off] = aK[r] + bck;
      Vb[off] = aV[r] + bcv;
    }
  }
}

// ---------------- persistent 8-iteration loop kernel ----------------
// Identical logic/numerics to R13 (bit-correct); ctrl counters padded to
// private 128B lines + throttled spin to kill the cross-XCD contention storm.
__global__ __launch_bounds__(256) void k_loop(const int* __restrict__ formula,
    const float* __restrict__ Kb, const float* __restrict__ Vb,
    const float* __restrict__ wf, float* __restrict__ vs8,
    float* __restrict__ op, float* __restrict__ pm, float* __restrict__ pl,
    int* __restrict__ assign, int* __restrict__ selb, int* __restrict__ ctrl) {
  __shared__ float kT[32 * 516];
  __shared__ float vsd[512 * 33];
  __shared__ float xv[256], qs[32], qpart[8][32];
  __shared__ float sS[512], sF[512], sRed[256];
  __shared__ float sO[8][32];
  __shared__ float sM, sQB;
  __shared__ float xo[256], hh[256];
  __shared__ int ssel, sna, sconf, suna, slastS, sglast, sdone, sac, sua;
  const int blk = blockIdx.x;
  const int bh = blk >> 2, c = blk & 3;
  const int b = bh >> 3, h = bh & 7;
  const int t = threadIdx.x;
  const float FAC1 = 1.0f - 0.9f;

  // one-time K/V chunk load into LDS
  {
    const float* kbh = Kb + ((size_t)bh * 2048 + c * 512) * 32;
    const float* vbh = Vb + ((size_t)bh * 2048 + c * 512) * 32;
    for (int base = 0; base < 64; ++base) {
      int idx = base * 256 + t;
      int j = idx >> 5, d = idx & 31;
      kT[d * 516 + j] = kbh[idx];
      vsd[j * 33 + d] = vbh[idx];
    }
  }
  __syncthreads();

  for (int it = 0; it < 8; ++it) {
    xv[t] = vs8[b * 256 + t];
    __syncthreads();
    {
      const float* wt = wf + WTIN_O;
      const int cc = h * 32 + (t & 31), seg = t >> 5;
      float part = 0.f;
      for (int k = seg * 32; k < seg * 32 + 32; ++k)
        part = fmaf(xv[k], wt[(size_t)k * 768 + cc], part);
      qpart[seg][t & 31] = part;
    }
    __syncthreads();
    if (t < 32) {
      float acc = qpart[0][t];
      #pragma unroll
      for (int s = 1; s < 8; ++s) acc += qpart[s][t];
      qs[t] = acc + wf[W_OFF[8] + h * 32 + t];
    }
    __syncthreads();
    if (t == 0) {
      const float* bk = wf + W_OFF[8] + 256;
      float s = 0.f;
      for (int d = 0; d < 32; ++d) s = fmaf(qs[d], bk[h * 32 + d], s);
      sQB = s;
    }
    __syncthreads();
    float qreg[32];
    #pragma unroll
    for (int d = 0; d < 32; ++d) qreg[d] = qs[d];
    const float qb = sQB;

    float mloc = -3.402823466e38f;
    #pragma unroll
    for (int ii = 0; ii < 2; ++ii) {
      int jl = ii * 256 + t;
      int n = b * 2048 + c * 512 + jl;
      bool sat = false;
      #pragma unroll
      for (int l = 0; l < 3; ++l) {
        int f = formula[n * 3 + l];
        int a = assign[b * 512 + (f >> 1)];
        sat = sat || (a == (f & 1));
      }
      float fac = sat ? FAC1 : 1.0f;
      float p = 0.f;
      #pragma unroll
      for (int d = 0; d < 32; ++d)
        p = fmaf(qreg[d], kT[d * 516 + jl], p);
      float s = fmaf(fac, p, qb);
      sS[jl] = s; sF[jl] = fac;
      mloc = fmaxf(mloc, s);
    }
    sRed[t] = mloc;
    __syncthreads();
    for (int st = 128; st > 0; st >>= 1) {
      if (t < st) sRed[t] = fmaxf(sRed[t], sRed[t + st]);
      __syncthreads();
    }
    if (t == 0) sM = sRed[0];
    __syncthreads();
    const float Mc = sM;

    {
      float u0 = expf(sS[t * 2] - Mc);
      float u1 = expf(sS[t * 2 + 1] - Mc);
      float ll = u0 + u1;
      sS[t * 2] = u0 * sF[t * 2];
      sS[t * 2 + 1] = u1 * sF[t * 2 + 1];
      __syncthreads();
      sRed[t] = ll;
      __syncthreads();
      for (int st = 128; st > 0; st >>= 1) {
        if (t < st) sRed[t] = sRed[t] + sRed[t + st];
        __syncthreads();
      }
    }
    {
      const int jg = t >> 5, d = t & 31;
      float acc = 0.f;
      for (int jj = 0; jj < 64; ++jj)
        acc = fmaf(sS[jg * 64 + jj], vsd[(jg * 64 + jj) * 33 + d], acc);
      sO[jg][d] = acc;
    }
    __syncthreads();
    if (t < 32) {
      float o = sO[0][t];
      #pragma unroll
      for (int g = 1; g < 8; ++g) o += sO[g][t];
      op[(size_t)(bh * 4 + c) * 32 + t] = o;
      if (t == 0) { pm[bh * 4 + c] = Mc; pl[bh * 4 + c] = sRed[0]; }
    }
    __syncthreads();
    // per-batch arrival (release); private line per batch
    if (t == 0) {
      __threadfence();
      int old = atomicAdd(&ctrl[C_BAT + b * 32], 1);
      slastS = (old == it * 32 + 31) ? 1 : 0;
    }
    __syncthreads();
    if (slastS) {
      __threadfence();   // acquire
      if (t == 0) { ssel = 512; sconf = 0; suna = 0; }
      {
        const int h2 = t >> 5, d = t & 31, bh2 = b * 8 + h2;
        float m0 = pm[bh2*4+0], m1 = pm[bh2*4+1], m2 = pm[bh2*4+2], m3 = pm[bh2*4+3];
        float M = fmaxf(fmaxf(m0, m1), fmaxf(m2, m3));
        float e0 = expf(m0 - M), e1 = expf(m1 - M), e2 = expf(m2 - M), e3 = expf(m3 - M);
        float den = e0 * pl[bh2*4+0];
        den = fmaf(e1, pl[bh2*4+1], den);
        den = fmaf(e2, pl[bh2*4+2], den);
        den = fmaf(e3, pl[bh2*4+3], den);
        float O = e0 * op[(size_t)(bh2*4+0)*32 + d];
        O = fmaf(e1, op[(size_t)(bh2*4+1)*32 + d], O);
        O = fmaf(e2, op[(size_t)(bh2*4+2)*32 + d], O);
        O = fmaf(e3, op[(size_t)(bh2*4+3)*32 + d], O);
        float bv = wf[W_OFF[8] + 512 + h2 * 32 + d];
        xo[h2 * 32 + d] = O / den + bv;
      }
      __syncthreads();
      {
        const float* wt = wf + WTOUT_O;
        float acc = 0.f;
        for (int k = 0; k < 256; ++k) acc = fmaf(xo[k], wt[(size_t)k * 256 + t], acc);
        float v = acc + wf[W_OFF[10] + t];
        vs8[b * 256 + t] = v;
        xv[t] = v;
      }
      __syncthreads();
      for (int ii = t; ii < 512; ii += 256)
        if (assign[b * 512 + ii] == 2) atomicMin(&ssel, ii);
      __syncthreads();
      const int sel = (ssel == 512) ? 0 : ssel;
      {
        const float* wt = wf + WTAP_O;
        float a = 0.f;
        for (int k = 0; k < 256; ++k) a = fmaf(xv[k], wt[(size_t)k * 256 + t], a);
        hh[t] = gelu_ref(a + wf[W_OFF[16] + t]);
      }
      __syncthreads();
      if (t == 0) {
        const float* w2 = wf + W_OFF[17];
        float l0 = 0.f, l1 = 0.f;
        for (int k = 0; k < 256; ++k) l0 = fmaf(hh[k], w2[k], l0);
        for (int k = 0; k < 256; ++k) l1 = fmaf(hh[k], w2[256 + k], l1);
        l0 += wf[W_OFF[18]];
        l1 += wf[W_OFF[18] + 1];
        int na = (l1 > l0) ? 1 : 0;
        assign[b * 512 + sel] = na;
        atomicExch(&selb[b], sel);
        sna = na;
      }
      __syncthreads();
      const int na = sna;
      int conf = 0, una = 0;
      for (int ii = t; ii < 2048; ii += 256) {
        int n = b * 2048 + ii;
        bool sat = false, alla = true;
        #pragma unroll
        for (int l = 0; l < 3; ++l) {
          int f = formula[n * 3 + l];
          int v = f >> 1;
          int a = (v == sel) ? na : assign[b * 512 + v];
          sat = sat || (a == (f & 1));
          alla = alla && (a != 2);
        }
        if (alla && !sat) conf = 1;
      }
      for (int ii = t; ii < 512; ii += 256) {
        int a = (ii == sel) ? na : assign[b * 512 + ii];
        if (a == 2) una = 1;
      }
      if (conf) atomicOr(&sconf, 1);
      if (una) atomicOr(&suna, 1);
      __syncthreads();
      if (t == 0) {
        if (sconf) atomicOr(&ctrl[C_CONF + it], 1);
        if (suna) atomicOr(&ctrl[C_UNA + it], 1);
        __threadfence();
        int old = atomicAdd(&ctrl[C_GBAR], 1);
        sglast = (old == it * 8 + 7) ? 1 : 0;
      }
      __syncthreads();
      if (sglast) {
        __threadfence();  // acquire
        if (t == 0) {
          sac = atomicAdd(&ctrl[C_CONF + it], 0);
          sua = atomicAdd(&ctrl[C_UNA + it], 0);
        }
        __syncthreads();
        if (sac && t < 8) {
          int s = atomicAdd(&selb[t], 0);
          assign[t * 512 + s] = 2;
        }
        __syncthreads();
        if (t == 0) {
          if (!sac && !sua) atomicExch(&ctrl[C_DONE], 1);
          __threadfence();
          atomicAdd(&ctrl[C_GREL], 1);   // grel -> it+1
        }
      }
    }
    // all blocks wait for iteration release (read-only line, throttled)
    if (t == 0) {
      while (__hip_atomic_load(&ctrl[C_GREL], __ATOMIC_ACQUIRE, __HIP_MEMORY_SCOPE_AGENT) < it + 1)
        __builtin_amdgcn_s_sleep(8);
      sdone = atomicAdd(&ctrl[C_DONE], 0);
    }
    __syncthreads();
    __threadfence();   // acquire for vs8/assign reads next iteration
    if (sdone) break;
  }
}

__global__ __launch_bounds__(256) void k_issat(const float* __restrict__ vs8,
    const int* __restrict__ assign, const float* __restrict__ wf,
    void* __restrict__ outv, const int* __restrict__ dflag) {
  const int b = blockIdx.x, t = threadIdx.x;
  const int isf32 = dflag[0];
  __shared__ float x[256], h[256];
  x[t] = vs8[b * 256 + t];   // mean of 512 identical rows == the row
  __syncthreads();
  const float* wt = wf + WTSP_O;
  float a = 0.f;
  for (int k = 0; k < 256; ++k) a = fmaf(x[k], wt[(size_t)k * 256 + t], a);
  h[t] = gelu_ref(a + wf[W_OFF[20] + t]);
  __syncthreads();
  if (t == 0) {
    const float* w2 = wf + W_OFF[21];
    float l = 0.f;
    for (int k = 0; k < 256; ++k) l = fmaf(h[k], w2[k], l);
    l += wf[W_OFF[22]];
    float sig = 1.f / (1.f + expf(-l));
    if (isf32) ((float*)outv)[b] = sig;
    else ((__hip_bfloat16*)outv)[b] = __float2bfloat16(sig);
  }
  for (int i = t; i < 512; i += 256) {
    float av = (float)assign[b * 512 + i];
    if (isf32) ((float*)outv)[8 + b * 512 + i] = av;
    else ((__hip_bfloat16*)outv)[8 + b * 512 + i] = __float2bfloat16(av);
  }
}

extern "C" void kernel_launch(void* const* d_in, const int* in_sizes, int n_in,
                              void* d_out, int out_size, void* d_ws, size_t ws_size,
                              hipStream_t stream) {
  (void)in_sizes; (void)n_in; (void)out_size; (void)ws_size;
  const int* formula = (const int*)d_in[0];
  float* wf = (float*)d_ws;
  SrcPtrs sp;
  for (int i = 0; i < W_N; ++i) sp.p[i] = d_in[i + 1];
  float* Kb   = wf + KB_O;
  float* Vb   = wf + VB_O;
  float* vs8  = wf + VS8_O;
  float* op   = wf + OP_O;
  float* pm   = wf + PM_O;
  float* pl   = wf + PL_O;
  int* iw     = (int*)(wf + FTOT);
  int* assign = iw;
  int* selb   = iw + 4096;
  int* ctrl   = iw + 4104;
  int* dflag  = iw + 4616;

  k_detect<<<1, 256, 0, stream>>>((const unsigned short*)d_in[1], dflag);
  k_convert<<<(W_TOT + 255) / 256, 256, 0, stream>>>(sp, wf, dflag);
  k_combine<<<513, 256, 0, stream>>>(wf);
  k_litproj<<<64, 256, 0, stream>>>(wf);
  k_init<<<16, 256, 0, stream>>>(vs8, assign, ctrl);
  k_base<<<1024, 256, 0, stream>>>(formula, wf, Kb, Vb);
  k_loop<<<256, 256, 0, stream>>>(formula, Kb, Vb, wf, vs8, op, pm, pl,
                                  assign, selb, ctrl);
  k_issat<<<8, 256, 0, stream>>>(vs8, assign, wf, d_out, dflag);
}

// Round 15
// 726.017 us; speedup vs baseline: 2.6473x; 2.6301x over previous
//
#include <hip/hip_runtime.h>
#include <hip/hip_bf16.h>

#pragma clang fp contract(off)

#define DEVI __device__ __forceinline__

constexpr int Bc = 8, Cc = 2048, Vc = 512, Hc = 256;

constexpr int W_N = 23;
constexpr int W_OFF[W_N] = {
  0,        524288,  655360,  655872,  656384,  656896,  787968,  788224,
  984832,   985600,  1051136, 1051392, 1116928, 1117184, 1117440, 1117444,
  1182980,  1183236, 1183748, 1183752, 1249288, 1249544, 1249800 };
constexpr int W_SZ[W_N] = {
  524288, 131072, 512, 512, 512, 131072, 256, 196608, 768,
  65536, 256, 65536, 256, 256, 1, 65536, 256, 512, 2, 65536, 256, 256, 1 };
constexpr int W_TOT = 1249804;
// slots: 0 lit_emb 1 ce_w1 2 ce_b1 3 ce_g 4 ce_beta 5 ce_w2 6 ce_b2
// 7 attn_in_w 8 attn_in_b 9 attn_out_w 10 attn_out_b 11 vs_w1 12 vs_b1
// 13 vs_w2 14 vs_b2 15 ap_w1 16 ap_b1 17 ap_w2 18 ap_b2 19 sp_w1 20 sp_b1
// 21 sp_w2 22 sp_b2

constexpr size_t WT1_O   = 1249808;            // ce_w1^T [256k][512r] (litproj input)
constexpr size_t WT2_O   = WT1_O   + 131072;   // ce_w2^T [512k][256r] (k_combine input)
constexpr size_t WTIN_O  = WT2_O   + 131072;   // attn_in^T [256k][768r]
constexpr size_t WTOUT_O = WTIN_O  + 196608;   // attn_out^T[256k][256r]
constexpr size_t WTV1_O  = WTOUT_O + 65536;    // (unused hole)
constexpr size_t WTAP_O  = WTV1_O  + 65536;    // ap_w1^T
constexpr size_t WTSP_O  = WTAP_O  + 65536;    // sp_w1^T
constexpr size_t WCK_O   = WTSP_O  + 65536;    // (Wk·ce_w2)^T [512k][256o]
constexpr size_t WCV_O   = WCK_O   + 131072;   // (Wv·ce_w2)^T
constexpr size_t BCK_O   = WCV_O   + 131072;   // Wk·ce_b2 (256)
constexpr size_t BCV_O   = BCK_O   + 256;      // Wv·ce_b2 (256)
constexpr size_t LP_O    = BCV_O   + 256;      // lit_emb @ ce_w1^T [1024][512]
constexpr size_t KB_O    = LP_O    + 524288;   // head-major [b*8+h][2048][32]
constexpr size_t VB_O    = KB_O    + 4194304;
constexpr size_t VS8_O   = VB_O    + 4194304;  // (8,256)
constexpr size_t OP_O    = VS8_O   + 2048;     // O partials [64bh][16c][32]
constexpr size_t PM_O    = OP_O    + 32768;    // chunk maxima [64][16]
constexpr size_t PL_O    = PM_O    + 1024;     // chunk L [64][16]
constexpr size_t FTOT    = PL_O    + 1024;     // ~45 MB + int area

// fused transpose specs (into k_convert)
constexpr int    TR_L2C[W_N]  = {0,8,0,0,0,9,0,8,0,8,0,0,0,0,0,8,0,0,0,8,0,0,0};
constexpr size_t TR_DST[W_N]  = {0,WT1_O,0,0,0,WT2_O,0,WTIN_O,0,WTOUT_O,0,0,0,0,0,WTAP_O,0,0,0,WTSP_O,0,0,0};
constexpr int    TR_ROWS[W_N] = {0,512,0,0,0,256,0,768,0,256,0,0,0,0,0,256,0,0,0,256,0,0,0};

struct SrcPtrs { const void* p[W_N]; };

DEVI float gelu_ref(float x) {
  return (x * (erff(x / 1.41421356237309504880f) + 1.0f)) * 0.5f;
}

__global__ __launch_bounds__(256) void k_detect(const unsigned short* __restrict__ lit,
                                                int* __restrict__ dflag) {
  __shared__ int red[256];
  int t = threadIdx.x, c = 0;
  for (int i = t; i < 4096; i += 256) {
    unsigned e = (lit[i] >> 7) & 0xFF;
    if (e >= 0x8F) c++;
  }
  red[t] = c;
  __syncthreads();
  for (int s = 128; s > 0; s >>= 1) {
    if (t < s) red[t] += red[t + s];
    __syncthreads();
  }
  if (t == 0) dflag[0] = (red[0] > 64) ? 1 : 0;
}

// convert + fused transpose copies
__global__ __launch_bounds__(256) void k_convert(SrcPtrs sp, float* __restrict__ wf,
                                                 const int* __restrict__ dflag) {
  int idx = blockIdx.x * 256 + threadIdx.x;
  if (idx >= W_TOT) return;
  const int isf32 = dflag[0];
  int i = 0;
  while (i + 1 < W_N && idx >= W_OFF[i + 1]) i++;
  int j = idx - W_OFF[i];
  float v = 0.f;
  if (j < W_SZ[i]) {
    if (isf32) v = ((const float*)sp.p[i])[j];
    else {
      unsigned int u = (unsigned int)((const unsigned short*)sp.p[i])[j] << 16;
      v = __uint_as_float(u);
    }
    int l2c = TR_L2C[i];
    if (l2c) {
      int r = j >> l2c, c = j & ((1 << l2c) - 1);
      wf[TR_DST[i] + (size_t)c * TR_ROWS[i] + r] = v;
    }
  }
  wf[idx] = v;
}

// Wck[k][o];  bck[o] = sum_m ce_b2[m]*Wk[o][m]
__global__ __launch_bounds__(256) void k_combine(float* __restrict__ wf) {
  const int blk = blockIdx.x, t = threadIdx.x;
  const float* wtin = wf + WTIN_O;
  if (blk < 512) {
    __shared__ float w2row[256];
    w2row[t] = wf[WT2_O + (size_t)blk * 256 + t];
    __syncthreads();
    float aK = 0.f, aV = 0.f;
    for (int m = 0; m < 256; ++m) {
      float w2 = w2row[m];
      aK = fmaf(w2, wtin[(size_t)m * 768 + 256 + t], aK);
      aV = fmaf(w2, wtin[(size_t)m * 768 + 512 + t], aV);
    }
    wf[WCK_O + (size_t)blk * 256 + t] = aK;
    wf[WCV_O + (size_t)blk * 256 + t] = aV;
  } else {
    float aK = 0.f, aV = 0.f;
    for (int m = 0; m < 256; ++m) {
      float b2 = wf[W_OFF[6] + m];
      aK = fmaf(b2, wtin[(size_t)m * 768 + 256 + t], aK);
      aV = fmaf(b2, wtin[(size_t)m * 768 + 512 + t], aV);
    }
    wf[BCK_O + t] = aK;
    wf[BCV_O + t] = aV;
  }
}

// LP = lit_emb @ ce_w1^T  (1024 x 512)
__global__ __launch_bounds__(256) void k_litproj(float* __restrict__ wf) {
  __shared__ __align__(16) float xs[16][256];
  const int t = threadIdx.x;
  const int l0 = blockIdx.x * 16;
  const float* lit = wf + W_OFF[0];
  for (int r = 0; r < 16; ++r)
    xs[r][t] = lit[(size_t)(l0 + r) * 256 + t];
  __syncthreads();
  const float* w1t = wf + WT1_O;
  float a0[16], a1[16];
  #pragma unroll
  for (int r = 0; r < 16; ++r) { a0[r] = 0.f; a1[r] = 0.f; }
  for (int k = 0; k < 256; k += 4) {
    float wa0 = w1t[(size_t)(k+0)*512 + t], wa1 = w1t[(size_t)(k+1)*512 + t];
    float wa2 = w1t[(size_t)(k+2)*512 + t], wa3 = w1t[(size_t)(k+3)*512 + t];
    float wb0 = w1t[(size_t)(k+0)*512 + 256 + t], wb1 = w1t[(size_t)(k+1)*512 + 256 + t];
    float wb2 = w1t[(size_t)(k+2)*512 + 256 + t], wb3 = w1t[(size_t)(k+3)*512 + 256 + t];
    #pragma unroll
    for (int r = 0; r < 16; ++r) {
      float4 x4 = *(const float4*)&xs[r][k];
      a0[r] = fmaf(x4.x, wa0, a0[r]);
      a0[r] = fmaf(x4.y, wa1, a0[r]);
      a0[r] = fmaf(x4.z, wa2, a0[r]);
      a0[r] = fmaf(x4.w, wa3, a0[r]);
      a1[r] = fmaf(x4.x, wb0, a1[r]);
      a1[r] = fmaf(x4.y, wb1, a1[r]);
      a1[r] = fmaf(x4.z, wb2, a1[r]);
      a1[r] = fmaf(x4.w, wb3, a1[r]);
    }
  }
  float* LP = wf + LP_O;
  for (int r = 0; r < 16; ++r) {
    LP[(size_t)(l0 + r) * 512 + t] = a0[r];
    LP[(size_t)(l0 + r) * 512 + 256 + t] = a1[r];
  }
}

__global__ __launch_bounds__(256) void k_init(float* __restrict__ vs8,
    int* __restrict__ assign, int* __restrict__ flags) {
  int idx = blockIdx.x * 256 + threadIdx.x;   // grid covers 4096
  assign[idx] = 2;
  if (idx < 2048) vs8[idx] = 0.f;
  if (idx < 4) flags[idx] = 0;   // 0: done, 1: conf, 2: una, 3: arrival
}

// ---------------- clause embedding: LP gather + LN + gelu + GEMM2 ----------------
__global__ __launch_bounds__(256) void k_base(const int* __restrict__ formula,
    const float* __restrict__ wf, float* __restrict__ Kb, float* __restrict__ Vb) {
  __shared__ __align__(16) float h1[16][516];
  __shared__ float red2[16][16];
  __shared__ float mv[16], vr[16];
  const int t = threadIdx.x;
  const int n0 = blockIdx.x * 16;
  const float* LP = wf + LP_O;
  const float* b1 = wf + W_OFF[2];
  for (int r = 0; r < 16; ++r) {
    int n = n0 + r;
    const float* p0 = LP + (size_t)formula[n*3+0] * 512;
    const float* p1 = LP + (size_t)formula[n*3+1] * 512;
    const float* p2 = LP + (size_t)formula[n*3+2] * 512;
    for (int c = t; c < 512; c += 256)
      h1[r][c] = (p0[c] + p1[c] + p2[c]) / 3.0f + b1[c];
  }
  __syncthreads();
  {
    const int r = t >> 4, l16 = t & 15;
    float s = 0.f;
    for (int j = 0; j < 32; ++j) s += h1[r][l16 + j * 16];
    red2[r][l16] = s;
  }
  __syncthreads();
  if (t < 16) {
    float s = 0.f;
    for (int i = 0; i < 16; ++i) s += red2[t][i];
    mv[t] = s / 512.0f;
  }
  __syncthreads();
  {
    const int r = t >> 4, l16 = t & 15;
    float m = mv[r], v = 0.f;
    for (int j = 0; j < 32; ++j) { float d = h1[r][l16 + j * 16] - m; v += d * d; }
    red2[r][l16] = v;
  }
  __syncthreads();
  if (t < 16) {
    float s = 0.f;
    for (int i = 0; i < 16; ++i) s += red2[t][i];
    vr[t] = s / 512.0f;
  }
  __syncthreads();
  {
    const float* g  = wf + W_OFF[3];
    const float* be = wf + W_OFF[4];
    for (int r = 0; r < 16; ++r) {
      float sd = sqrtf(vr[r] + 1e-5f);
      for (int c = t; c < 512; c += 256) {
        float val = (h1[r][c] - mv[r]) / sd * g[c] + be[c];
        h1[r][c] = gelu_ref(val);
      }
    }
  }
  __syncthreads();
  {
    const float* wck = wf + WCK_O;
    const float* wcv = wf + WCV_O;
    float aK[16], aV[16];
    #pragma unroll
    for (int r = 0; r < 16; ++r) { aK[r] = 0.f; aV[r] = 0.f; }
    for (int k = 0; k < 512; k += 4) {
      float ck0 = wck[(size_t)(k+0)*256 + t], ck1 = wck[(size_t)(k+1)*256 + t];
      float ck2 = wck[(size_t)(k+2)*256 + t], ck3 = wck[(size_t)(k+3)*256 + t];
      float cv0 = wcv[(size_t)(k+0)*256 + t], cv1 = wcv[(size_t)(k+1)*256 + t];
      float cv2 = wcv[(size_t)(k+2)*256 + t], cv3 = wcv[(size_t)(k+3)*256 + t];
      #pragma unroll
      for (int r = 0; r < 16; ++r) {
        float4 x4 = *(const float4*)&h1[r][k];
        aK[r] = fmaf(x4.x, ck0, aK[r]);
        aK[r] = fmaf(x4.y, ck1, aK[r]);
        aK[r] = fmaf(x4.z, ck2, aK[r]);
        aK[r] = fmaf(x4.w, ck3, aK[r]);
        aV[r] = fmaf(x4.x, cv0, aV[r]);
        aV[r] = fmaf(x4.y, cv1, aV[r]);
        aV[r] = fmaf(x4.z, cv2, aV[r]);
        aV[r] = fmaf(x4.w, cv3, aV[r]);
      }
    }
    float bck = wf[BCK_O + t], bcv = wf[BCV_O + t];
    const int h = t >> 5, d = t & 31;
    for (int r = 0; r < 16; ++r) {
      int n = n0 + r;
      int b = n >> 11, j = n & 2047;
      size_t off = ((size_t)(b * 8 + h) * 2048 + j) * 32 + d;
      Kb[off] = aK[r] + bck;
      Vb[off] = aV[r] + bcv;
    }
  }
}

// ---------------- per-iteration: chunked attention (1024 blocks, 128 keys) ----------------
__global__ __launch_bounds__(256) void k_attn_part(const int* __restrict__ formula,
    const int* __restrict__ assign, const float* __restrict__ Kb,
    const float* __restrict__ Vb, const float* __restrict__ wf,
    const float* __restrict__ vs8, float* __restrict__ op, float* __restrict__ pm,
    float* __restrict__ pl, const int* __restrict__ flags) {
  if (flags[0]) return;
  __shared__ float xv[256], qs[32], qpart[8][32];
  __shared__ float sW[128], sRed[256];
  __shared__ float sO[8][32];
  __shared__ float sM, sQB;
  const int blk = blockIdx.x;          // 1024 = 64 bh * 16 c
  const int bh = blk >> 4, c = blk & 15;
  const int b = bh >> 3, h = bh & 7;
  const int t = threadIdx.x;
  const float FAC1 = 1.0f - 0.9f;

  xv[t] = vs8[b * 256 + t];
  __syncthreads();
  // q projection: 8 partial chains of 32 k each, tree-combined
  {
    const float* wt = wf + WTIN_O;
    const int cc = h * 32 + (t & 31), seg = t >> 5;
    float part = 0.f;
    for (int k = seg * 32; k < seg * 32 + 32; ++k)
      part = fmaf(xv[k], wt[(size_t)k * 768 + cc], part);
    qpart[seg][t & 31] = part;
  }
  __syncthreads();
  if (t < 32) {
    float acc = qpart[0][t];
    #pragma unroll
    for (int s = 1; s < 8; ++s) acc += qpart[s][t];
    qs[t] = acc + wf[W_OFF[8] + h * 32 + t];
  }
  __syncthreads();
  if (t == 0) {
    const float* bk = wf + W_OFF[8] + 256;
    float s = 0.f;
    for (int d = 0; d < 32; ++d) s = fmaf(qs[d], bk[h * 32 + d], s);
    sQB = s;
  }
  __syncthreads();
  float qreg[32];
  #pragma unroll
  for (int d = 0; d < 32; ++d) qreg[d] = qs[d];
  const float qb = sQB;
  const float* kbh = Kb + (size_t)bh * 2048 * 32;
  const float* vbh = Vb + (size_t)bh * 2048 * 32;

  // phase A: thread t<128 handles key j = c*128 + t
  float mloc = -3.402823466e38f;
  float sval = 0.f, fval = 1.0f;
  if (t < 128) {
    int j = c * 128 + t;
    int n = b * 2048 + j;
    bool sat = false;
    #pragma unroll
    for (int l = 0; l < 3; ++l) {
      int f = formula[n * 3 + l];
      int a = assign[b * 512 + (f >> 1)];
      sat = sat || (a == (f & 1));
    }
    float fac = sat ? FAC1 : 1.0f;
    const float4* kr4 = (const float4*)(kbh + (size_t)j * 32);
    float p = 0.f;
    #pragma unroll
    for (int g = 0; g < 8; ++g) {
      float4 kk = kr4[g];
      p = fmaf(qreg[4*g+0], kk.x, p);
      p = fmaf(qreg[4*g+1], kk.y, p);
      p = fmaf(qreg[4*g+2], kk.z, p);
      p = fmaf(qreg[4*g+3], kk.w, p);
    }
    float s = fmaf(fac, p, qb);
    sval = s; fval = fac;
    mloc = s;
  }
  sRed[t] = mloc;
  __syncthreads();
  for (int st = 128; st > 0; st >>= 1) {
    if (t < st) sRed[t] = fmaxf(sRed[t], sRed[t + st]);
    __syncthreads();
  }
  if (t == 0) sM = sRed[0];
  __syncthreads();
  const float Mc = sM;

  // phase B1: u, Lc, w = u*fac
  {
    float ll = 0.f;
    if (t < 128) {
      float u = expf(sval - Mc);
      ll = u;
      sW[t] = u * fval;
    }
    sRed[t] = ll;
    __syncthreads();
    for (int st = 128; st > 0; st >>= 1) {
      if (t < st) sRed[t] = sRed[t] + sRed[t + st];
      __syncthreads();
    }
  }
  // phase B2: PV partials; group jg handles 16 keys
  {
    const int jg = t >> 5, d = t & 31;
    float acc = 0.f;
    const float* vbase = vbh + (size_t)(c * 128 + jg * 16) * 32 + d;
    for (int jj = 0; jj < 16; ++jj)
      acc = fmaf(sW[jg * 16 + jj], vbase[(size_t)jj * 32], acc);
    sO[jg][d] = acc;
  }
  __syncthreads();
  if (t < 32) {
    float o = sO[0][t];
    #pragma unroll
    for (int g = 1; g < 8; ++g) o += sO[g][t];
    op[(size_t)(bh * 16 + c) * 32 + t] = o;
    if (t == 0) { pm[bh * 16 + c] = Mc; pl[bh * 16 + c] = sRed[0]; }
  }
}

// flash-merge (16 chunks) + out-proj + sel + ap MLP + conflict + fused finalize
__global__ __launch_bounds__(256) void k_update(const int* __restrict__ formula,
    const float* __restrict__ op, const float* __restrict__ pm,
    const float* __restrict__ pl, const float* __restrict__ wf,
    float* __restrict__ vs8, int* __restrict__ assign, int* __restrict__ selb,
    int* __restrict__ flags) {
  if (flags[0]) return;
  const int b = blockIdx.x, t = threadIdx.x;
  __shared__ float xo[256], xv[256], hh[256];
  __shared__ int ssel, sna, sconf, suna, slast;
  if (t == 0) { ssel = 512; sconf = 0; suna = 0; }
  // merge 16 chunks: thread (h = t>>5, d = t&31)
  {
    const int h = t >> 5, d = t & 31, bh = b * 8 + h;
    float M = pm[bh * 16];
    #pragma unroll
    for (int i = 1; i < 16; ++i) M = fmaxf(M, pm[bh * 16 + i]);
    float den = 0.f, O = 0.f;
    #pragma unroll
    for (int i = 0; i < 16; ++i) {
      float e = expf(pm[bh * 16 + i] - M);
      den = fmaf(e, pl[bh * 16 + i], den);
      O = fmaf(e, op[(size_t)(bh * 16 + i) * 32 + d], O);
    }
    float bv = wf[W_OFF[8] + 512 + h * 32 + d];
    xo[h * 32 + d] = O / den + bv;
  }
  __syncthreads();
  // out-proj
  {
    const float* wt = wf + WTOUT_O;
    float acc = 0.f;
    for (int k = 0; k < 256; ++k) acc = fmaf(xo[k], wt[(size_t)k * 256 + t], acc);
    float v = acc + wf[W_OFF[10] + t];
    vs8[b * 256 + t] = v;
    xv[t] = v;
  }
  __syncthreads();
  for (int i = t; i < 512; i += 256)
    if (assign[b * 512 + i] == 2) atomicMin(&ssel, i);
  __syncthreads();
  const int sel = (ssel == 512) ? 0 : ssel;
  {
    const float* wt = wf + WTAP_O;
    float a = 0.f;
    for (int k = 0; k < 256; ++k) a = fmaf(xv[k], wt[(size_t)k * 256 + t], a);
    hh[t] = gelu_ref(a + wf[W_OFF[16] + t]);
  }
  __syncthreads();
  if (t == 0) {
    const float* w2 = wf + W_OFF[17];
    float l0 = 0.f, l1 = 0.f;
    for (int k = 0; k < 256; ++k) l0 = fmaf(hh[k], w2[k], l0);
    for (int k = 0; k < 256; ++k) l1 = fmaf(hh[k], w2[256 + k], l1);
    l0 += wf[W_OFF[18]];
    l1 += wf[W_OFF[18] + 1];
    int na = (l1 > l0) ? 1 : 0;
    assign[b * 512 + sel] = na;
    selb[b] = sel;
    sna = na;
  }
  __syncthreads();
  const int na = sna;
  int conf = 0, una = 0;
  for (int i = t; i < 2048; i += 256) {
    int n = b * 2048 + i;
    bool sat = false, alla = true;
    #pragma unroll
    for (int l = 0; l < 3; ++l) {
      int f = formula[n * 3 + l];
      int v = f >> 1;
      int a = (v == sel) ? na : assign[b * 512 + v];
      sat = sat || (a == (f & 1));
      alla = alla && (a != 2);
    }
    if (alla && !sat) conf = 1;
  }
  for (int i = t; i < 512; i += 256) {
    int a = (i == sel) ? na : assign[b * 512 + i];
    if (a == 2) una = 1;
  }
  if (conf) atomicOr(&sconf, 1);
  if (una) atomicOr(&suna, 1);
  __syncthreads();
  if (t == 0) {
    if (sconf) atomicOr(&flags[1], 1);
    if (suna) atomicOr(&flags[2], 1);
    __threadfence();
    int old = atomicAdd(&flags[3], 1);
    slast = (old == 7) ? 1 : 0;
  }
  __syncthreads();
  if (slast) {
    __threadfence();
    const int ac = flags[1], ua = flags[2];
    if (ac && t < 8) assign[t * 512 + selb[t]] = 2;
    if (t == 0) {
      if (!ac && !ua) flags[0] = 1;
      flags[1] = 0;
      flags[2] = 0;
      flags[3] = 0;
    }
  }
}

__global__ __launch_bounds__(256) void k_issat(const float* __restrict__ vs8,
    const int* __restrict__ assign, const float* __restrict__ wf,
    void* __restrict__ outv, const int* __restrict__ dflag) {
  const int b = blockIdx.x, t = threadIdx.x;
  const int isf32 = dflag[0];
  __shared__ float x[256], h[256];
  x[t] = vs8[b * 256 + t];   // mean of 512 identical rows == the row
  __syncthreads();
  const float* wt = wf + WTSP_O;
  float a = 0.f;
  for (int k = 0; k < 256; ++k) a = fmaf(x[k], wt[(size_t)k * 256 + t], a);
  h[t] = gelu_ref(a + wf[W_OFF[20] + t]);
  __syncthreads();
  if (t == 0) {
    const float* w2 = wf + W_OFF[21];
    float l = 0.f;
    for (int k = 0; k < 256; ++k) l = fmaf(h[k], w2[k], l);
    l += wf[W_OFF[22]];
    float sig = 1.f / (1.f + expf(-l));
    if (isf32) ((float*)outv)[b] = sig;
    else ((__hip_bfloat16*)outv)[b] = __float2bfloat16(sig);
  }
  for (int i = t; i < 512; i += 256) {
    float av = (float)assign[b * 512 + i];
    if (isf32) ((float*)outv)[8 + b * 512 + i] = av;
    else ((__hip_bfloat16*)outv)[8 + b * 512 + i] = __float2bfloat16(av);
  }
}

extern "C" void kernel_launch(void* const* d_in, const int* in_sizes, int n_in,
                              void* d_out, int out_size, void* d_ws, size_t ws_size,
                              hipStream_t stream) {
  (void)in_sizes; (void)n_in; (void)out_size; (void)ws_size;
  const int* formula = (const int*)d_in[0];
  float* wf = (float*)d_ws;
  SrcPtrs sp;
  for (int i = 0; i < W_N; ++i) sp.p[i] = d_in[i + 1];
  float* Kb   = wf + KB_O;
  float* Vb   = wf + VB_O;
  float* vs8  = wf + VS8_O;
  float* op   = wf + OP_O;
  float* pm   = wf + PM_O;
  float* pl   = wf + PL_O;
  int* iw     = (int*)(wf + FTOT);
  int* assign = iw;
  int* selb   = iw + 4096;
  int* flags  = iw + 4104;
  int* dflag  = iw + 4108;

  k_detect<<<1, 256, 0, stream>>>((const unsigned short*)d_in[1], dflag);
  k_convert<<<(W_TOT + 255) / 256, 256, 0, stream>>>(sp, wf, dflag);
  k_combine<<<513, 256, 0, stream>>>(wf);
  k_litproj<<<64, 256, 0, stream>>>(wf);
  k_init<<<16, 256, 0, stream>>>(vs8, assign, flags);
  k_base<<<1024, 256, 0, stream>>>(formula, wf, Kb, Vb);
  for (int it = 0; it < 8; ++it) {
    k_attn_part<<<1024, 256, 0, stream>>>(formula, assign, Kb, Vb, wf, vs8,
                                          op, pm, pl, flags);
    k_update<<<8, 256, 0, stream>>>(formula, op, pm, pl, wf, vs8, assign,
                                    selb, flags);
  }
  k_issat<<<8, 256, 0, stream>>>(vs8, assign, wf, d_out, dflag);
}